// Round 7
// baseline (61.615 us; speedup 1.0000x reference)
//
#include <hip/hip_runtime.h>

// out[i][j] = x[i][j] + sum_p ln(p) * x[(i - p) mod 8192][j]
// x: (8192, 4096) fp32. Rolling-retirement sliding window, f32x4 lanes:
// each thread owns one float4 column slot and R=16 consecutive output rows.
// acc[i] completes at t = i+19 (shift-0 last) -> store immediately; live
// accumulator window stays ~20 x 4 = 80 VGPR. 16B/lane loads (1KB/wave
// transactions, the m13 copy-ceiling config) to test read-granularity.

#define ROWS 8192
#define COLS 4096
#define COLS4 (COLS / 4)   // 1024 float4 per row
#define LOG2_COLS4 10
#define R 16               // output rows per thread
#define MAXSHIFT 19
#define NXCD 8

typedef float f32x4 __attribute__((ext_vector_type(4)));

__constant__ constexpr int   SHIFT[9] = {0, 2, 3, 5, 7, 11, 13, 17, 19};
__constant__ constexpr float COEF[9]  = {
    1.0f,
    0.69314718055994530942f,  // ln 2
    1.09861228866810969140f,  // ln 3
    1.60943791243410037460f,  // ln 5
    1.94591014905531330511f,  // ln 7
    2.39789527279837054406f,  // ln 11
    2.56494935746153673605f,  // ln 13
    2.83321334405621608025f,  // ln 17
    2.94443897916644046001f   // ln 19
};

__global__ __launch_bounds__(256, 4) void spectral_kernel(
    const f32x4* __restrict__ x, f32x4* __restrict__ out) {
  // 2048 blocks; bijective XCD-contiguous swizzle (2048 % 8 == 0):
  // XCD k owns blocks k*256..k*256+255 -> contiguous rows, halo stays in L2.
  const int sblk = (blockIdx.x & (NXCD - 1)) * (2048 / NXCD) + (blockIdx.x >> 3);
  const int g = sblk * blockDim.x + threadIdx.x;
  const int j = g & (COLS4 - 1);            // float4 column slot
  const int b = (g >> LOG2_COLS4) * R;      // first output row of this thread

  f32x4 acc[R];
#pragma unroll
  for (int k = 0; k < R; ++k) acc[k] = (f32x4)(0.f);

#pragma unroll
  for (int t = 0; t < R + MAXSHIFT; ++t) {
    const int r = (b - MAXSHIFT + t) & (ROWS - 1);
    const f32x4 v = x[(r << LOG2_COLS4) + j];
#pragma unroll
    for (int s = 0; s < 9; ++s) {
      const int k = t - MAXSHIFT + SHIFT[s];   // output row (rel. to b) fed by v
      if (k >= 0 && k < R) {                   // folds at compile time
        acc[k] = v * COEF[s] + acc[k];
      }
    }
    // Rolling retirement: acc[t-MAXSHIFT] just received its final (shift-0)
    // contribution -> store now, freeing its registers.
    if (t >= MAXSHIFT) {
      const int k = t - MAXSHIFT;
      __builtin_nontemporal_store(acc[k], &out[((b + k) << LOG2_COLS4) + j]);
    }
  }
}

extern "C" void kernel_launch(void* const* d_in, const int* in_sizes, int n_in,
                              void* d_out, int out_size, void* d_ws, size_t ws_size,
                              hipStream_t stream) {
  const f32x4* x = (const f32x4*)d_in[0];
  f32x4* out = (f32x4*)d_out;
  const int total_threads = (ROWS / R) * COLS4;  // 512 * 1024 = 524288
  const int block = 256;
  const int grid = total_threads / block;        // 2048
  spectral_kernel<<<grid, block, 0, stream>>>(x, out);
}

// Round 8
// 42.849 us; speedup vs baseline: 1.4380x; 1.4380x over previous
//
#include <hip/hip_runtime.h>

// out[i][j] = x[i][j] + sum_p ln(p) * x[(i - p) mod 8192][j]
// x: (8192, 4096) fp32. Rolling-retirement sliding window, f32x2 lanes:
// each thread owns one f32x2 column slot and R=16 consecutive output rows.
// acc[i] is complete at t = i+19 (shift-0 last) -> store immediately, so
// only ~20 accumulators (~40 VGPR) are ever live. __launch_bounds__(256,8)
// keeps VGPR <= 64 -> 8 waves/SIMD; 4096 blocks = 16384 waves for latency
// hiding. Measured best (R5): 43.2 us, FETCH 67 MB (L3-resident reads),
// WRITE 131 MB, occ 68-80%. R=32 (R6) and f32x4 (R7) variants both lost
// L3 residency and wave count -> regressed; this config is the keeper.

#define ROWS 8192
#define COLS 4096
#define COLS2 (COLS / 2)   // 2048 f32x2 per row
#define LOG2_COLS2 11
#define R 16               // output rows per thread
#define MAXSHIFT 19
#define NXCD 8

typedef float f32x2 __attribute__((ext_vector_type(2)));

__constant__ constexpr int   SHIFT[9] = {0, 2, 3, 5, 7, 11, 13, 17, 19};
__constant__ constexpr float COEF[9]  = {
    1.0f,
    0.69314718055994530942f,  // ln 2
    1.09861228866810969140f,  // ln 3
    1.60943791243410037460f,  // ln 5
    1.94591014905531330511f,  // ln 7
    2.39789527279837054406f,  // ln 11
    2.56494935746153673605f,  // ln 13
    2.83321334405621608025f,  // ln 17
    2.94443897916644046001f   // ln 19
};

__global__ __launch_bounds__(256, 8) void spectral_kernel(
    const f32x2* __restrict__ x, f32x2* __restrict__ out) {
  // 4096 blocks; bijective XCD-contiguous swizzle (4096 % 8 == 0):
  // XCD k owns blocks k*512..k*512+511 -> contiguous rows, halo stays in L2.
  const int sblk = (blockIdx.x & (NXCD - 1)) * (4096 / NXCD) + (blockIdx.x >> 3);
  const int g = sblk * blockDim.x + threadIdx.x;
  const int j = g & (COLS2 - 1);            // f32x2 column slot
  const int b = (g >> LOG2_COLS2) * R;      // first output row of this thread

  f32x2 acc[R];
#pragma unroll
  for (int k = 0; k < R; ++k) acc[k] = (f32x2)(0.f);

#pragma unroll
  for (int t = 0; t < R + MAXSHIFT; ++t) {
    const int r = (b - MAXSHIFT + t) & (ROWS - 1);
    const f32x2 v = x[(r << LOG2_COLS2) + j];
#pragma unroll
    for (int s = 0; s < 9; ++s) {
      const int k = t - MAXSHIFT + SHIFT[s];   // output row (rel. to b) fed by v
      if (k >= 0 && k < R) {                   // folds at compile time
        acc[k] = v * COEF[s] + acc[k];
      }
    }
    // Rolling retirement: acc[t-MAXSHIFT] just received its final (shift-0)
    // contribution -> store now, freeing its registers.
    if (t >= MAXSHIFT) {
      const int k = t - MAXSHIFT;
      __builtin_nontemporal_store(acc[k], &out[((b + k) << LOG2_COLS2) + j]);
    }
  }
}

extern "C" void kernel_launch(void* const* d_in, const int* in_sizes, int n_in,
                              void* d_out, int out_size, void* d_ws, size_t ws_size,
                              hipStream_t stream) {
  const f32x2* x = (const f32x2*)d_in[0];
  f32x2* out = (f32x2*)d_out;
  const int total_threads = (ROWS / R) * COLS2;  // 512 * 2048 = 1048576
  const int block = 256;
  const int grid = total_threads / block;        // 4096
  spectral_kernel<<<grid, block, 0, stream>>>(x, out);
}